// Round 1
// baseline (227.123 us; speedup 1.0000x reference)
//
#include <hip/hip_runtime.h>

typedef _Float16 half_t;
typedef _Float16 hx8 __attribute__((ext_vector_type(8)));
typedef _Float16 hx4 __attribute__((ext_vector_type(4)));
typedef float fx4 __attribute__((ext_vector_type(4)));

#define LOG2E 1.44269504088896f
#define TAU 0.1f
#define NSPLIT 8

// ---------------- Kernel 1: fused ztrans + MLP, full-chip -------------------
// (unchanged from baseline)
__global__ __launch_bounds__(128) void mlpz_kernel(
    const float* __restrict__ Z, const float* __restrict__ W1,
    const float* __restrict__ b1, const float* __restrict__ W2,
    const float* __restrict__ b2, half_t* __restrict__ T,
    half_t* __restrict__ Zth)
{
  __shared__ float Ztile[32*132];       // 16.9 KB
  __shared__ half_t Hs[2][16*136];      // 8.7 KB
  const int tid = threadIdx.x;
  const int w = tid >> 6, lane = tid & 63;
  const int q = lane >> 4, c = lane & 15;
  const int rb = blockIdx.x*32;
  const int wrow = rb + w*16;

#pragma unroll
  for (int i=0;i<8;++i) {
    int fid = i*128 + tid;
    int r = fid >> 5, c4 = (fid & 31)*4;
    *(fx4*)(&Ztile[r*132 + c4]) = *(const fx4*)(Z + (size_t)(rb + r)*128 + c4);
  }
  __syncthreads();

  {
    const int d = tid;
#pragma unroll
    for (int i=0;i<4;++i) {
      hx8 hv;
#pragma unroll
      for (int u=0;u<8;++u) hv[u] = (half_t)Ztile[(i*8 + u)*132 + d];
      *(hx8*)(Zth + (size_t)d*8192 + rb + i*8) = hv;
    }
  }

  hx8 zb[4];
#pragma unroll
  for (int ks=0;ks<4;++ks) {
    fx4 a = *(const fx4*)(&Ztile[(w*16 + c)*132 + ks*32 + q*8]);
    fx4 b = *(const fx4*)(&Ztile[(w*16 + c)*132 + ks*32 + q*8 + 4]);
#pragma unroll
    for (int u=0;u<4;++u) { zb[ks][u] = (half_t)a[u]; zb[ks][4+u] = (half_t)b[u]; }
  }

  fx4 acc[8];
#pragma unroll
  for (int mt=0;mt<8;++mt) acc[mt] = (fx4){0.f,0.f,0.f,0.f};
#pragma unroll
  for (int mt=0;mt<8;++mt)
#pragma unroll
    for (int ks=0;ks<4;++ks) {
      hx8 aw;
#pragma unroll
      for (int j=0;j<8;++j)
        aw[j] = (half_t)W1[(size_t)(ks*32 + q*8 + j)*128 + mt*16 + c];
      acc[mt] = __builtin_amdgcn_mfma_f32_16x16x32_f16(aw, zb[ks], acc[mt], 0,0,0);
    }
#pragma unroll
  for (int mt=0;mt<8;++mt) {
    fx4 bias = *(const fx4*)(b1 + mt*16 + 4*q);
    hx4 hv;
#pragma unroll
    for (int i=0;i<4;++i) {
      float h = acc[mt][i] + bias[i];
      hv[i] = (half_t)(h > 0.f ? h : 0.f);
    }
    *(hx4*)(&Hs[w][c*136 + mt*16 + 4*q]) = hv;
  }

  hx8 hb[4];
#pragma unroll
  for (int ks=0;ks<4;++ks) hb[ks] = *(const hx8*)(&Hs[w][c*136 + ks*32 + q*8]);
#pragma unroll
  for (int mt=0;mt<8;++mt) acc[mt] = (fx4){0.f,0.f,0.f,0.f};
#pragma unroll
  for (int mt=0;mt<8;++mt)
#pragma unroll
    for (int ks=0;ks<4;++ks) {
      hx8 aw;
#pragma unroll
      for (int j=0;j<8;++j)
        aw[j] = (half_t)W2[(size_t)(ks*32 + q*8 + j)*128 + mt*16 + c];
      acc[mt] = __builtin_amdgcn_mfma_f32_16x16x32_f16(aw, hb[ks], acc[mt], 0,0,0);
    }
#pragma unroll
  for (int mt=0;mt<8;++mt) {
    fx4 bias = *(const fx4*)(b2 + mt*16 + 4*q);
    hx4 tv;
#pragma unroll
    for (int i=0;i<4;++i) tv[i] = (half_t)(acc[mt][i] + bias[i]);
    *(hx4*)(T + (size_t)(wrow + c)*128 + mt*16 + 4*q) = tv;
  }
}

// ---------------- Kernel 2: flash attention partials (v2: occupancy) -------
// R-occ restructure: 1024 blocks = 128 query-blocks (64 rows) x 8 key-splits.
// nt removed (16 q-rows/wave) -> 4096 waves total = 16/CU potential.
// Zbuf DELETED: PV A-fragments read straight from global Zt. kh = bx&7
// matches the 8-XCD round-robin, so each XCD's L2 holds only its own 256KB
// key-slice of T and Zt -> az reads are L2-hot. LDS = Tbuf only (32 KB)
// -> 4 blocks/CU if VGPR<=128 (est ~110). Barriers/DMA position/softmax
// identical to baseline, de-duplicated over nt.
// NO wide hoisted operand arrays (R5/R10). __launch_bounds__ kept at (256,2).
__global__ __launch_bounds__(256,2) void flash_kernel(
    const half_t* __restrict__ T, const half_t* __restrict__ Zt,
    half_t* __restrict__ Pacc, float* __restrict__ Pm, float* __restrict__ Pl)
{
  __shared__ half_t Tbuf[2][16*512];    // 32 KB — the ONLY LDS
  const int tid = threadIdx.x;
  const int w = tid >> 6, lane = tid & 63;
  const int q = lane >> 4, c = lane & 15;
  const int bx = blockIdx.x;
  const int qb = bx >> 3, kh = bx & 7;  // 128 query-blocks x 8 key-splits
  const int wrow = qb*64 + w*16;
  const int sw = (c & 7) * 8;

  hx8 bq[4];
#pragma unroll
  for (int ks=0;ks<4;++ks)
    bq[ks] = *(const hx8*)(T + (size_t)(wrow + c)*128 + ks*32 + q*8);

  fx4 oacc[8];
#pragma unroll
  for (int mtd=0;mtd<8;++mtd) oacc[mtd] = (fx4){0.f,0.f,0.f,0.f};
  float m_run = -1e30f;
  float l_run = 0.f;

  const int kbase = kh*1024;

  auto issue_loads = [&](int kt0, int b) {
    // 16 T-fragment fills spread over 4 waves (4 each)
#pragma unroll
    for (int i=0;i<4;++i) {
      int f = w*4 + i, mt = f >> 2, ks = f & 3;
      const half_t* gp = T + (size_t)(kt0 + mt*16 + c)*128 + ks*32 + q*8;
      half_t* lp = &Tbuf[b][f*512 + lane*8];
      __builtin_amdgcn_global_load_lds(
          (const __attribute__((address_space(1))) void*)gp,
          (__attribute__((address_space(3))) void*)lp, 16, 0, 0);
    }
  };

  issue_loads(kbase, 0);

  for (int t=0;t<16;++t) {
    const int cur = t & 1;
    __syncthreads();                    // drains DMA fills of cur + publishes
    half_t* Tcur = Tbuf[cur];
    half_t* Psw  = &Tbuf[cur][w*1024]; // per-wave 16x64 P^T region (dead Tcur)

    // ---- scores ----
    fx4 sacc[4];
#pragma unroll
    for (int mt=0;mt<4;++mt) sacc[mt] = (fx4){0.f,0.f,0.f,0.f};
#pragma unroll
    for (int ks=0;ks<4;++ks)
#pragma unroll
      for (int mt=0;mt<4;++mt) {
        hx8 ak = *(const hx8*)(&Tcur[(mt*4+ks)*512 + lane*8]);
        sacc[mt] = __builtin_amdgcn_mfma_f32_16x16x32_f16(ak, bq[ks], sacc[mt], 0,0,0);
      }

    // ---- online softmax ----
    float mx = -1e30f;
#pragma unroll
    for (int mt=0;mt<4;++mt)
#pragma unroll
      for (int i=0;i<4;++i) mx = fmaxf(mx, sacc[mt][i]);
    mx = fmaxf(mx, __shfl_xor(mx, 16, 64));
    mx = fmaxf(mx, __shfl_xor(mx, 32, 64));
    float mnew = fmaxf(m_run, mx);
    float alpha = __builtin_amdgcn_exp2f((m_run - mnew)*LOG2E);
    m_run = mnew;
    float nb = mnew*LOG2E;
    float rs = 0.f;
    hx4 pk[4];
#pragma unroll
    for (int mt=0;mt<4;++mt)
#pragma unroll
      for (int i=0;i<4;++i) {
        float p = __builtin_amdgcn_exp2f(sacc[mt][i]*LOG2E - nb);
        rs += p;
        pk[mt][i] = (half_t)p;
      }
    rs += __shfl_xor(rs, 16, 64);
    rs += __shfl_xor(rs, 32, 64);
    l_run = l_run*alpha + rs;
#pragma unroll
    for (int mtd=0;mtd<8;++mtd)
#pragma unroll
      for (int i=0;i<4;++i) oacc[mtd][i] *= alpha;

    __syncthreads();                    // all scores reads of Tcur done
    if (t < 15) issue_loads(kbase + (t+1)*64, cur ^ 1);

    // P^T into dead Tcur region, per-wave, xor-swizzled
#pragma unroll
    for (int mt=0;mt<4;++mt)
      *(hx4*)(&Psw[c*64 + ((mt*16 + 4*q) ^ sw)]) = pk[mt];

    // ---- PV: az fragments straight from global (XCD-L2-hot) ----
    const half_t* zcol = Zt + (size_t)c*8192 + kbase + t*64 + q*8;
#pragma unroll
    for (int ks2=0;ks2<2;++ks2) {
      hx8 bp = *(const hx8*)(&Psw[c*64 + ((ks2*32 + q*8) ^ sw)]);
#pragma unroll
      for (int mtd=0;mtd<8;++mtd) {
        hx8 az = *(const hx8*)(zcol + (size_t)mtd*16*8192 + ks2*32);
        oacc[mtd] = __builtin_amdgcn_mfma_f32_16x16x32_f16(az, bp, oacc[mtd], 0,0,0);
      }
    }
  }

  // epilogue — partial-row index matches merge's (qb128, kh, rr) layout
  float inv = 1.0f / l_run;
  const size_t prow = (size_t)(((qb >> 1)*8 + kh)*128 + (qb & 1)*64 + w*16 + c);
#pragma unroll
  for (int mtd=0;mtd<8;++mtd) {
    hx4 ov;
#pragma unroll
    for (int i=0;i<4;++i) ov[i] = (half_t)(oacc[mtd][i]*inv);
    *(hx4*)(Pacc + prow*128 + mtd*16 + 4*q) = ov;
  }
  if (q == 0) {
    Pm[prow] = m_run;
    Pl[prow] = l_run;
  }
}

// ---------------- Kernel 3: merge NSPLIT key-split partials ----------------
// (unchanged from baseline)
__global__ __launch_bounds__(256) void merge_kernel(
    const float* __restrict__ Z, const half_t* __restrict__ Pacc,
    const float* __restrict__ Pm, const float* __restrict__ Pl,
    float* __restrict__ out)
{
  const int th = blockIdx.x*256 + threadIdx.x;
  const int r = th >> 5, cg = th & 31;
  const int qb = r >> 7, rr = r & 127;
  float mk[NSPLIT], lk[NSPLIT];
  float M = -1e30f;
#pragma unroll
  for (int k=0;k<NSPLIT;++k) {
    int p = qb*NSPLIT + k;
    mk[k] = Pm[p*128 + rr];
    lk[k] = Pl[p*128 + rr];
    M = fmaxf(M, mk[k]);
  }
  float L = 0.f, wk[NSPLIT];
#pragma unroll
  for (int k=0;k<NSPLIT;++k) { wk[k] = lk[k]*__builtin_amdgcn_exp2f((mk[k]-M)*LOG2E); L += wk[k]; }
  float o0=0.f,o1=0.f,o2=0.f,o3=0.f;
#pragma unroll
  for (int k=0;k<NSPLIT;++k) {
    int p = qb*NSPLIT + k;
    hx4 v = *(const hx4*)(Pacc + ((size_t)p*128 + rr)*128 + cg*4);
    o0 += wk[k]*(float)v[0]; o1 += wk[k]*(float)v[1];
    o2 += wk[k]*(float)v[2]; o3 += wk[k]*(float)v[3];
  }
  float invL = 1.0f / L;
  fx4 zv = *(const fx4*)(Z + (size_t)r*128 + cg*4);
  fx4 res;
  res[0] = (1.f-TAU)*zv[0] + TAU*o0*invL;
  res[1] = (1.f-TAU)*zv[1] + TAU*o1*invL;
  res[2] = (1.f-TAU)*zv[2] + TAU*o2*invL;
  res[3] = (1.f-TAU)*zv[3] + TAU*o3*invL;
  *(fx4*)(out + (size_t)r*128 + cg*4) = res;
}

extern "C" void kernel_launch(void* const* d_in, const int* in_sizes, int n_in,
                              void* d_out, int out_size, void* d_ws, size_t ws_size,
                              hipStream_t stream) {
  const float* Z  = (const float*)d_in[0];
  const float* W1 = (const float*)d_in[1];
  const float* b1 = (const float*)d_in[2];
  const float* W2 = (const float*)d_in[3];
  const float* b2 = (const float*)d_in[4];
  float* out = (float*)d_out;

  char* ws = (char*)d_ws;
  const size_t NBLK = 64 * NSPLIT;                                // 512 partial groups (x128 rows)
  half_t* Thi  = (half_t*)(ws);                                   // 2 MB
  half_t* Zth  = (half_t*)(ws + (size_t)2*1024*1024);             // 2 MB
  half_t* Pacc = (half_t*)(ws + (size_t)4*1024*1024);             // 16 MB
  float*  Pm   = (float*)(ws + (size_t)4*1024*1024 + NBLK*128*128*2);
  float*  Pl   = Pm + NBLK*128;

  hipLaunchKernelGGL(mlpz_kernel,  dim3(256),  dim3(128), 0, stream, Z, W1, b1, W2, b2, Thi, Zth);
  hipLaunchKernelGGL(flash_kernel, dim3(128*NSPLIT), dim3(256), 0, stream, Thi, Zth, Pacc, Pm, Pl);
  hipLaunchKernelGGL(merge_kernel, dim3(1024), dim3(256), 0, stream, Z, Pacc, Pm, Pl, out);
}

// Round 2
// 138.933 us; speedup vs baseline: 1.6348x; 1.6348x over previous
//
#include <hip/hip_runtime.h>

typedef _Float16 half_t;
typedef _Float16 hx8 __attribute__((ext_vector_type(8)));
typedef _Float16 hx4 __attribute__((ext_vector_type(4)));
typedef float fx4 __attribute__((ext_vector_type(4)));

#define LOG2E 1.44269504088896f
#define TAU 0.1f
#define NSPLIT 8

// ---------------- Kernel 1: fused ztrans + MLP (v2: 8 waves/CU) ------------
// 512 blocks x 16 rows, 256 threads (4 waves). Wave w computes output-col
// frags mt in {2w, 2w+1}; shared Hs + barrier between layers. W gathers per
// lane halved vs v1 (128 scalar loads), 4x the waves/CU (2 -> 8).
__global__ __launch_bounds__(256) void mlpz_kernel(
    const float* __restrict__ Z, const float* __restrict__ W1,
    const float* __restrict__ b1, const float* __restrict__ W2,
    const float* __restrict__ b2, half_t* __restrict__ T,
    half_t* __restrict__ Zth)
{
  __shared__ float Ztile[16*132];       // 8.45 KB
  __shared__ half_t Hs[16*136];         // 4.35 KB
  const int tid = threadIdx.x;
  const int w = tid >> 6, lane = tid & 63;
  const int q = lane >> 4, c = lane & 15;
  const int rb = blockIdx.x*16;

  // stage 16 Z-rows (512 fx4 slots / 256 threads = 2 iters, coalesced)
#pragma unroll
  for (int i=0;i<2;++i) {
    int fid = i*256 + tid;
    int r = fid >> 5, c4 = (fid & 31)*4;
    *(fx4*)(&Ztile[r*132 + c4]) = *(const fx4*)(Z + (size_t)(rb + r)*128 + c4);
  }
  __syncthreads();

  // emit Zth[d][rb..rb+16) (fp16); thread owns dim d = tid&127, row-half tid>>7
  {
    const int d = tid & 127, h = tid >> 7;
    hx8 hv;
#pragma unroll
    for (int u=0;u<8;++u) hv[u] = (half_t)Ztile[(h*8 + u)*132 + d];
    *(hx8*)(Zth + (size_t)d*8192 + rb + h*8) = hv;
  }

  // layer-1 B-frags (data rows, same 16 rows for all waves)
  hx8 zb[4];
#pragma unroll
  for (int ks=0;ks<4;++ks) {
    fx4 a = *(const fx4*)(&Ztile[c*132 + ks*32 + q*8]);
    fx4 b = *(const fx4*)(&Ztile[c*132 + ks*32 + q*8 + 4]);
#pragma unroll
    for (int u=0;u<4;++u) { zb[ks][u] = (half_t)a[u]; zb[ks][4+u] = (half_t)b[u]; }
  }

  // ---- layer 1: wave w owns mt = 2w, 2w+1 ----
#pragma unroll
  for (int m2=0;m2<2;++m2) {
    const int mt = w*2 + m2;
    fx4 acc = (fx4){0.f,0.f,0.f,0.f};
#pragma unroll
    for (int ks=0;ks<4;++ks) {
      hx8 aw;                           // A[m][k] = W1[k][m]
#pragma unroll
      for (int j=0;j<8;++j)
        aw[j] = (half_t)W1[(size_t)(ks*32 + q*8 + j)*128 + mt*16 + c];
      acc = __builtin_amdgcn_mfma_f32_16x16x32_f16(aw, zb[ks], acc, 0,0,0);
    }
    fx4 bias = *(const fx4*)(b1 + mt*16 + 4*q);
    hx4 hv;
#pragma unroll
    for (int i=0;i<4;++i) {
      float h = acc[i] + bias[i];
      hv[i] = (half_t)(h > 0.f ? h : 0.f);
    }
    *(hx4*)(&Hs[c*136 + mt*16 + 4*q]) = hv;
  }
  __syncthreads();

  // ---- layer 2 ----
  hx8 hb[4];
#pragma unroll
  for (int ks=0;ks<4;++ks) hb[ks] = *(const hx8*)(&Hs[c*136 + ks*32 + q*8]);
#pragma unroll
  for (int m2=0;m2<2;++m2) {
    const int mt = w*2 + m2;
    fx4 acc = (fx4){0.f,0.f,0.f,0.f};
#pragma unroll
    for (int ks=0;ks<4;++ks) {
      hx8 aw;
#pragma unroll
      for (int j=0;j<8;++j)
        aw[j] = (half_t)W2[(size_t)(ks*32 + q*8 + j)*128 + mt*16 + c];
      acc = __builtin_amdgcn_mfma_f32_16x16x32_f16(aw, hb[ks], acc, 0,0,0);
    }
    fx4 bias = *(const fx4*)(b2 + mt*16 + 4*q);
    hx4 tv;
#pragma unroll
    for (int i=0;i<4;++i) tv[i] = (half_t)(acc[i] + bias[i]);
    *(hx4*)(T + (size_t)(rb + c)*128 + mt*16 + 4*q) = tv;
  }
}

// ---------------- Kernel 2: flash attention partials (v3) ------------------
// Round-0 structure restored (Zbuf in LDS: ALL operand reads in lgkmcnt
// domain; vmcnt queue belongs exclusively to prefetch DMA) but with 32-key
// tiles: LDS 64->32 KB, sacc halved -> ~110 VGPR -> 4 blocks/CU = 16
// waves/CU (was 2 blocks = 8 waves). 32 iterations, same 2-barrier + DMA-
// after-sync_b discipline. Round-1 lesson: NEVER put MFMA-operand global
// loads after issue_loads — vmcnt FIFO drains the prefetch. NO wide hoisted
// operand arrays. NEVER __launch_bounds__(256,3+).
__global__ __launch_bounds__(256,2) void flash_kernel(
    const half_t* __restrict__ T, const half_t* __restrict__ Zt,
    half_t* __restrict__ Pacc, float* __restrict__ Pm, float* __restrict__ Pl)
{
  __shared__ half_t Tbuf[2][8*512];     // 16 KB
  __shared__ half_t Zbuf[2][8*512];     // 16 KB
  const int tid = threadIdx.x;
  const int w = tid >> 6, lane = tid & 63;
  const int q = lane >> 4, c = lane & 15;
  const int bx = blockIdx.x;
  const int qb = bx >> 3, kh = bx & 7;
  const int wrow = qb*128 + w*32;
  const int sw = (c & 3) * 8;           // xor-swizzle within 32-half P rows

  hx8 bq[2][4];
#pragma unroll
  for (int nt=0;nt<2;++nt)
#pragma unroll
    for (int ks=0;ks<4;++ks)
      bq[nt][ks] = *(const hx8*)(T + (size_t)(wrow + nt*16 + c)*128 + ks*32 + q*8);

  fx4 oacc[8][2];
#pragma unroll
  for (int mtd=0;mtd<8;++mtd)
#pragma unroll
    for (int nt=0;nt<2;++nt) oacc[mtd][nt] = (fx4){0.f,0.f,0.f,0.f};
  float m_run[2] = {-1e30f,-1e30f};
  float l_run[2] = {0.f,0.f};

  const int kbase = kh*1024;

  auto issue_loads = [&](int kt0, int b) {
    if (w < 2) {
#pragma unroll
      for (int i=0;i<4;++i) {
        int f = w*4 + i, mt = f >> 2, ks = f & 3;
        const half_t* gp = T + (size_t)(kt0 + mt*16 + c)*128 + ks*32 + q*8;
        half_t* lp = &Tbuf[b][f*512 + lane*8];
        __builtin_amdgcn_global_load_lds(
            (const __attribute__((address_space(1))) void*)gp,
            (__attribute__((address_space(3))) void*)lp, 16, 0, 0);
      }
    } else {
#pragma unroll
      for (int i=0;i<4;++i) {
        int f2 = (w-2)*4 + i;           // = mtd (dim-group)
        const half_t* gp = Zt + (size_t)(f2*16 + c)*8192 + kt0 + q*8;
        half_t* lp = &Zbuf[b][f2*512 + lane*8];
        __builtin_amdgcn_global_load_lds(
            (const __attribute__((address_space(1))) void*)gp,
            (__attribute__((address_space(3))) void*)lp, 16, 0, 0);
      }
    }
  };

  issue_loads(kbase, 0);

  for (int t=0;t<32;++t) {
    const int cur = t & 1;
    __syncthreads();                    // drains DMA fills of cur + publishes
    half_t* Tcur = Tbuf[cur];
    half_t* Zcur = Zbuf[cur];
    half_t* Psw  = &Tbuf[cur][w*1024];  // per-wave 32x32 P^T (dead Tcur)

    // ---- scores (32 keys x 32 q-rows per wave) ----
    fx4 sacc[2][2];
#pragma unroll
    for (int mt=0;mt<2;++mt)
#pragma unroll
      for (int nt=0;nt<2;++nt) sacc[mt][nt] = (fx4){0.f,0.f,0.f,0.f};
#pragma unroll
    for (int ks=0;ks<4;++ks)
#pragma unroll
      for (int mt=0;mt<2;++mt) {
        hx8 ak = *(const hx8*)(&Tcur[(mt*4+ks)*512 + lane*8]);
        sacc[mt][0] = __builtin_amdgcn_mfma_f32_16x16x32_f16(ak, bq[0][ks], sacc[mt][0], 0,0,0);
        sacc[mt][1] = __builtin_amdgcn_mfma_f32_16x16x32_f16(ak, bq[1][ks], sacc[mt][1], 0,0,0);
      }

    // ---- online softmax ----
    hx4 pk[2][2];
#pragma unroll
    for (int nt=0;nt<2;++nt) {
      float mx = -1e30f;
#pragma unroll
      for (int mt=0;mt<2;++mt)
#pragma unroll
        for (int i=0;i<4;++i) mx = fmaxf(mx, sacc[mt][nt][i]);
      mx = fmaxf(mx, __shfl_xor(mx, 16, 64));
      mx = fmaxf(mx, __shfl_xor(mx, 32, 64));
      float mnew = fmaxf(m_run[nt], mx);
      float alpha = __builtin_amdgcn_exp2f((m_run[nt]-mnew)*LOG2E);
      m_run[nt] = mnew;
      float nb = mnew*LOG2E;
      float rs = 0.f;
#pragma unroll
      for (int mt=0;mt<2;++mt) {
#pragma unroll
        for (int i=0;i<4;++i) {
          float p = __builtin_amdgcn_exp2f(sacc[mt][nt][i]*LOG2E - nb);
          rs += p;
          pk[nt][mt][i] = (half_t)p;
        }
      }
      rs += __shfl_xor(rs, 16, 64);
      rs += __shfl_xor(rs, 32, 64);
      l_run[nt] = l_run[nt]*alpha + rs;
#pragma unroll
      for (int mtd=0;mtd<8;++mtd)
#pragma unroll
        for (int i=0;i<4;++i) oacc[mtd][nt][i] *= alpha;
    }

    __syncthreads();                    // all scores reads of Tcur done
    if (t < 31) issue_loads(kbase + (t+1)*32, cur ^ 1);

    // P^T into dead Tcur region, per-wave, xor-swizzled (rows = 32 halfs)
#pragma unroll
    for (int nt=0;nt<2;++nt)
#pragma unroll
      for (int mt=0;mt<2;++mt)
        *(hx4*)(&Psw[(nt*16 + c)*32 + ((mt*16 + 4*q) ^ sw)]) = pk[nt][mt];

    // ---- PV (single 32-key step) ----
    {
      hx8 bp0 = *(const hx8*)(&Psw[(c     )*32 + ((q*8) ^ sw)]);
      hx8 bp1 = *(const hx8*)(&Psw[(16 + c)*32 + ((q*8) ^ sw)]);
#pragma unroll
      for (int mtd=0;mtd<8;++mtd) {
        hx8 az = *(const hx8*)(&Zcur[mtd*512 + lane*8]);
        oacc[mtd][0] = __builtin_amdgcn_mfma_f32_16x16x32_f16(az, bp0, oacc[mtd][0], 0,0,0);
        oacc[mtd][1] = __builtin_amdgcn_mfma_f32_16x16x32_f16(az, bp1, oacc[mtd][1], 0,0,0);
      }
    }
  }

#pragma unroll
  for (int nt=0;nt<2;++nt) {
    float inv = 1.0f / l_run[nt];
    const size_t rowg = (size_t)(bx*128 + w*32 + nt*16 + c);
#pragma unroll
    for (int mtd=0;mtd<8;++mtd) {
      hx4 ov;
#pragma unroll
      for (int i=0;i<4;++i) ov[i] = (half_t)(oacc[mtd][nt][i]*inv);
      *(hx4*)(Pacc + rowg*128 + mtd*16 + 4*q) = ov;
    }
    if (q == 0) {
      Pm[rowg] = m_run[nt];
      Pl[rowg] = l_run[nt];
    }
  }
}

// ---------------- Kernel 3: merge NSPLIT key-split partials ----------------
// (unchanged from round-0 baseline)
__global__ __launch_bounds__(256) void merge_kernel(
    const float* __restrict__ Z, const half_t* __restrict__ Pacc,
    const float* __restrict__ Pm, const float* __restrict__ Pl,
    float* __restrict__ out)
{
  const int th = blockIdx.x*256 + threadIdx.x;
  const int r = th >> 5, cg = th & 31;
  const int qb = r >> 7, rr = r & 127;
  float mk[NSPLIT], lk[NSPLIT];
  float M = -1e30f;
#pragma unroll
  for (int k=0;k<NSPLIT;++k) {
    int p = qb*NSPLIT + k;
    mk[k] = Pm[p*128 + rr];
    lk[k] = Pl[p*128 + rr];
    M = fmaxf(M, mk[k]);
  }
  float L = 0.f, wk[NSPLIT];
#pragma unroll
  for (int k=0;k<NSPLIT;++k) { wk[k] = lk[k]*__builtin_amdgcn_exp2f((mk[k]-M)*LOG2E); L += wk[k]; }
  float o0=0.f,o1=0.f,o2=0.f,o3=0.f;
#pragma unroll
  for (int k=0;k<NSPLIT;++k) {
    int p = qb*NSPLIT + k;
    hx4 v = *(const hx4*)(Pacc + ((size_t)p*128 + rr)*128 + cg*4);
    o0 += wk[k]*(float)v[0]; o1 += wk[k]*(float)v[1];
    o2 += wk[k]*(float)v[2]; o3 += wk[k]*(float)v[3];
  }
  float invL = 1.0f / L;
  fx4 zv = *(const fx4*)(Z + (size_t)r*128 + cg*4);
  fx4 res;
  res[0] = (1.f-TAU)*zv[0] + TAU*o0*invL;
  res[1] = (1.f-TAU)*zv[1] + TAU*o1*invL;
  res[2] = (1.f-TAU)*zv[2] + TAU*o2*invL;
  res[3] = (1.f-TAU)*zv[3] + TAU*o3*invL;
  *(fx4*)(out + (size_t)r*128 + cg*4) = res;
}

extern "C" void kernel_launch(void* const* d_in, const int* in_sizes, int n_in,
                              void* d_out, int out_size, void* d_ws, size_t ws_size,
                              hipStream_t stream) {
  const float* Z  = (const float*)d_in[0];
  const float* W1 = (const float*)d_in[1];
  const float* b1 = (const float*)d_in[2];
  const float* W2 = (const float*)d_in[3];
  const float* b2 = (const float*)d_in[4];
  float* out = (float*)d_out;

  char* ws = (char*)d_ws;
  const size_t NBLK = 64 * NSPLIT;                                // 512
  half_t* Thi  = (half_t*)(ws);                                   // 2 MB
  half_t* Zth  = (half_t*)(ws + (size_t)2*1024*1024);             // 2 MB
  half_t* Pacc = (half_t*)(ws + (size_t)4*1024*1024);             // 16 MB
  float*  Pm   = (float*)(ws + (size_t)4*1024*1024 + NBLK*128*128*2);
  float*  Pl   = Pm + NBLK*128;

  hipLaunchKernelGGL(mlpz_kernel,  dim3(512),  dim3(256), 0, stream, Z, W1, b1, W2, b2, Thi, Zth);
  hipLaunchKernelGGL(flash_kernel, dim3(NBLK), dim3(256), 0, stream, Thi, Zth, Pacc, Pm, Pl);
  hipLaunchKernelGGL(merge_kernel, dim3(1024), dim3(256), 0, stream, Z, Pacc, Pm, Pl, out);
}